// Round 11
// baseline (886.064 us; speedup 1.0000x reference)
//
#include <hip/hip_runtime.h>

// QuantumQLSTM on MI355X — R22: 8-wave in-wave matvec, ONE barrier per step.
// Cost model (fits R13/R14/R19/R20/R21): step = instr/SIMD x cadence + syncs +
// chain; cadence ~2-2.5cy at 2 waves/SIMD, ~4cy at 1 wave/SIMD (R21's miss).
// R22 = R21's zh-in-SGPR structure at 8 waves: every wave redundantly computes
// all 12 cols from ONE ds_read_b128 of Hbuf (lane l holds Hv[4l..4l+3]; 64
// lanes = full vector), 12 wsum + 12 readlane -> zh wave-uniform in SGPRs.
// Lanes 0-31 own h=32w+l (32-63 mirror, bit-identical). Double-buffered Hbuf
// -> single lds_barrier. zx packed to 12 floats/(t,h) (wire 0 drops out).
// Predicted: rec 321 -> 210-245us, total ~470-505. absmax unchanged (R21 ran
// this exact math).
//
// History: R1 4250 -> ... -> R14 600 (rec 339) -> R16 600 (nt null) ->
// R18 891 (fusion REGRESSION) -> R19 578.6 (rec 321) -> R20 581.7 (NULL:
// wide trans free) -> R21 639 (rec 380: 1 wave/SIMD cadence REGRESSION) -> R22.

#define T_DIM 512
#define B_DIM 256
#define D_DIM 256
#define H_DIM 256
#define DH    512   // D + H
#define NG    16    // 4 gates * NQ(4)
#define NZ    12    // packed zx floats per (t,b): 4 gates x wires 1..3
#define XPAD  68    // Xc/Wc LDS row stride (floats): 16B-aligned, 2-way max
#define INV2PI 0.15915494309189535f

typedef float f32x4 __attribute__((ext_vector_type(4)));  // clang-native 16B vec

#if __has_builtin(__builtin_amdgcn_fractf) && __has_builtin(__builtin_amdgcn_cosf)
#define TRIG_REV 1
#else
#define TRIG_REV 0
#endif

__device__ __forceinline__ float fast_sigmoid(float x) {
    return 1.0f / (1.0f + __expf(-x));
}
__device__ __forceinline__ float fast_tanh(float x) {
    // |x| <= ~2.1 here (|C| <= 0.557/(1-0.731)); exp safe
    float e = __expf(2.0f * x);
    return (e - 1.0f) / (e + 1.0f);
}
// cos(2*pi*x), x in revolutions (v_fract + v_cos; verified R19)
__device__ __forceinline__ float cos_rev(float x) {
#if TRIG_REV
    return __builtin_amdgcn_cosf(__builtin_amdgcn_fractf(x));
#else
    return __cosf(x * 6.283185307179586f);
#endif
}
// x + dpp_mov(x): one reduction level, VALU pipe.
template <int CTRL, int RM, int BM, bool BC>
__device__ __forceinline__ float dadd(float x) {
    return x + __int_as_float(
        __builtin_amdgcn_update_dpp(0, __float_as_int(x), CTRL, RM, BM, BC));
}
// full-wave sum; result valid in lane 63 (verified since R11)
__device__ __forceinline__ float wsum(float x) {
    x = dadd<0x111, 0xf, 0xf, true >(x);   // row_shr:1
    x = dadd<0x112, 0xf, 0xf, true >(x);   // row_shr:2
    x = dadd<0x114, 0xf, 0xf, true >(x);   // row_shr:4
    x = dadd<0x118, 0xf, 0xf, true >(x);   // row_shr:8
    x = dadd<0x142, 0xa, 0xf, false>(x);   // row_bcast:15
    x = dadd<0x143, 0xc, 0xf, false>(x);   // row_bcast:31 -> lane63
    return x;
}
// lane63 value -> wave-uniform SGPR broadcast (verified R21)
__device__ __forceinline__ float bcast63(float x) {
    return __int_as_float(__builtin_amdgcn_readlane(__float_as_int(x), 63));
}
// Barrier draining ONLY the LDS pipe (no vmcnt): global ops float across steps.
__device__ __forceinline__ void lds_barrier() {
    __asm__ volatile("s_waitcnt lgkmcnt(0)\n\ts_barrier" ::: "memory");
}

// -------------------- zx precompute (R14 4x4 register tiling; R22: packed-12
// output in REVOLUTIONS — wire 0 dropped: zx[(t*B+b)*12 + q*3 + (j-1)])
__global__ __launch_bounds__(256) void zx_kernel(
    const float* __restrict__ x,
    const float* __restrict__ Wf, const float* __restrict__ Wi,
    const float* __restrict__ Wu, const float* __restrict__ Wo,
    const float* __restrict__ bf, const float* __restrict__ bi,
    const float* __restrict__ bu, const float* __restrict__ bo,
    const float* __restrict__ phf, const float* __restrict__ phi,
    const float* __restrict__ phu, const float* __restrict__ pho,
    float* __restrict__ zx)
{
    __shared__ float Xc[256][XPAD];
    __shared__ float Wc[NG][XPAD];
    const int tid = threadIdx.x;
    const int rt  = tid >> 2;           // 0..63
    const int qt  = tid & 3;            // gate index 0..3

    const float* bv = (qt == 0) ? bf : (qt == 1) ? bi : (qt == 2) ? bu : bo;
    const float* pv = (qt == 0) ? phf : (qt == 1) ? phi : (qt == 2) ? phu : pho;
    float acc[4][4];
    #pragma unroll
    for (int j = 0; j < 4; ++j) {
        const float bj = bv[j] + pv[j];
        acc[0][j] = bj; acc[1][j] = bj; acc[2][j] = bj; acc[3][j] = bj;
    }

    const long base = (long)blockIdx.x * 256 * D_DIM;

    for (int c = 0; c < 4; ++c) {                 // k-chunk of 64
        const int k0 = c * 64;
        #pragma unroll
        for (int it = 0; it < 16; ++it) {
            const int e = tid + it * 256;
            const int row = e >> 4, col4 = (e & 15) * 4;
            *(float4*)&Xc[row][col4] =
                *(const float4*)(x + base + (long)row * D_DIM + k0 + col4);
        }
        {
            const int q16 = tid >> 4, col4 = (tid & 15) * 4;
            const int g = q16 >> 2, qj = q16 & 3;
            const float* W = (g == 0) ? Wf : (g == 1) ? Wi : (g == 2) ? Wu : Wo;
            *(float4*)&Wc[q16][col4] = *(const float4*)(W + qj * DH + k0 + col4);
        }
        __syncthreads();

        #pragma unroll 4
        for (int kk = 0; kk < 16; ++kk) {
            const int k4 = kk * 4;
            float4 xv0 = *(float4*)&Xc[rt][k4];
            float4 xv1 = *(float4*)&Xc[rt +  64][k4];
            float4 xv2 = *(float4*)&Xc[rt + 128][k4];
            float4 xv3 = *(float4*)&Xc[rt + 192][k4];
            float4 wv0 = *(float4*)&Wc[4 * qt + 0][k4];
            float4 wv1 = *(float4*)&Wc[4 * qt + 1][k4];
            float4 wv2 = *(float4*)&Wc[4 * qt + 2][k4];
            float4 wv3 = *(float4*)&Wc[4 * qt + 3][k4];
            #pragma unroll
            for (int i = 0; i < 4; ++i) {
                const float4 xv = (i == 0) ? xv0 : (i == 1) ? xv1 : (i == 2) ? xv2 : xv3;
                acc[i][0] = fmaf(xv.x, wv0.x, fmaf(xv.y, wv0.y, fmaf(xv.z, wv0.z, fmaf(xv.w, wv0.w, acc[i][0]))));
                acc[i][1] = fmaf(xv.x, wv1.x, fmaf(xv.y, wv1.y, fmaf(xv.z, wv1.z, fmaf(xv.w, wv1.w, acc[i][1]))));
                acc[i][2] = fmaf(xv.x, wv2.x, fmaf(xv.y, wv2.y, fmaf(xv.z, wv2.z, fmaf(xv.w, wv2.w, acc[i][2]))));
                acc[i][3] = fmaf(xv.x, wv3.x, fmaf(xv.y, wv3.y, fmaf(xv.z, wv3.z, fmaf(xv.w, wv3.w, acc[i][3]))));
            }
        }
        __syncthreads();
    }

    // packed-12 store: wires 1..3 only, scaled to revolutions
    const long orow = (long)blockIdx.x * 256;
    #pragma unroll
    for (int i = 0; i < 4; ++i) {
        const long off = (orow + rt + 64 * i) * NZ + qt * 3;
        zx[off + 0] = acc[i][1] * INV2PI;
        zx[off + 1] = acc[i][2] * INV2PI;
        zx[off + 2] = acc[i][3] * INV2PI;
    }
}

// -------------------- sequential core: ONE block, 512 threads (8 waves)
// Per-wave redundant matvec (zh in SGPRs); lanes 0-31 own h=32w+l; 1 barrier.
__global__ __launch_bounds__(512) void rec_kernel(
    const float* __restrict__ Wf, const float* __restrict__ Wi,
    const float* __restrict__ Wu, const float* __restrict__ Wo,
    const float* __restrict__ zx,
    float* __restrict__ hv_tab,   // [T][H]; hv_tab[-H..-1] is a scratch pad row
    float* __restrict__ c_fin)    // [H]
{
    __shared__ float Hbuf[2][H_DIM];       // double-buffered Hv
    const int tid  = threadIdx.x;          // 0..511
    const int lane = tid & 63;
    const int wv   = tid >> 6;             // wave 0..7
    const int hh   = 32 * wv + (lane & 31);  // owned h (lanes 32-63 mirror)
    const bool own = (lane < 32);

    // 12 recurrent columns, this lane's Hv slice h=4*lane..+3, revolutions
    float4 W[12];
    #pragma unroll
    for (int c = 0; c < 12; ++c) {
        const int g = c / 3, j = c % 3 + 1;
        const float* Wg = (g == 0) ? Wf : (g == 1) ? Wi : (g == 2) ? Wu : Wo;
        float4 w = *(const float4*)(Wg + j * DH + 256 + 4 * lane);
        w.x *= INV2PI; w.y *= INV2PI; w.z *= INV2PI; w.w *= INV2PI;
        W[c] = w;
    }

    float C = 0.0f, Hprev = 0.0f;
    if (tid < H_DIM) Hbuf[1][tid] = 0.0f;  // Hv[-1] = 0
    lds_barrier();

    // zx register double-buffer (depth 2): 3 float4 = 12 angles per t
    float4 za0, za1, za2, zb0, zb1, zb2;
    {
        const float4* p0 = (const float4*)(zx + (long)hh * NZ);
        const float4* p1 = (const float4*)(zx + ((long)B_DIM + hh) * NZ);
        za0 = p0[0]; za1 = p0[1]; za2 = p0[2];
        zb0 = p1[0]; zb1 = p1[1]; zb2 = p1[2];
    }

    auto step = [&](int t, float4& z0, float4& z1, float4& z2) {
        // longest-latency first: full Hv[t-1] via this wave's 64 lanes
        const float4 Hv4 = *(const float4*)&Hbuf[(t + 1) & 1][4 * lane];
        // early-issue global store of Hv[t-1] (floats across the step)
        if (own) hv_tab[(long)(t - 1) * H_DIM + hh] = Hprev;

        // in-wave matvec: 12 cols x dot4, wave-sum, SGPR broadcast
        float p[12];
        #pragma unroll
        for (int c = 0; c < 12; ++c)
            p[c] = fmaf(W[c].x, Hv4.x, fmaf(W[c].y, Hv4.y,
                       fmaf(W[c].z, Hv4.z, W[c].w * Hv4.w)));
        float zh[12];
        #pragma unroll
        for (int c = 0; c < 12; ++c) zh[c] = bcast63(wsum(p[c]));

        // gates for own h (lanes 32-63 mirror, bit-identical)
        const float f_ = fast_sigmoid(cos_rev(z0.x + zh[0]) * cos_rev(z0.y + zh[1])  * cos_rev(z0.z + zh[2]));
        const float i_ = fast_sigmoid(cos_rev(z0.w + zh[3]) * cos_rev(z1.x + zh[4])  * cos_rev(z1.y + zh[5]));
        const float g_ = fast_tanh   (cos_rev(z1.z + zh[6]) * cos_rev(z1.w + zh[7])  * cos_rev(z2.x + zh[8]));
        const float o_ = fast_sigmoid(cos_rev(z2.y + zh[9]) * cos_rev(z2.z + zh[10]) * cos_rev(z2.w + zh[11]));

        // prefetch zx[t+2] (floats across steps; overwrites consumed regs)
        {
            const int tp = (t + 2 < T_DIM) ? (t + 2) : t;
            const float4* pp = (const float4*)(zx + ((long)tp * B_DIM + hh) * NZ);
            z0 = pp[0]; z1 = pp[1]; z2 = pp[2];
        }

        C = fmaf(f_, C, i_ * g_);
        const float Hnew = o_ * fast_tanh(C);
        if (own) Hbuf[t & 1][hh] = Hnew;   // 8 waves x 32 lanes cover 256
        Hprev = Hnew;
        lds_barrier();                     // the ONLY barrier per step
    };

    for (int t = 0; t < T_DIM; t += 2) {
        step(t,     za0, za1, za2);
        step(t + 1, zb0, zb1, zb2);
    }

    if (own) {
        hv_tab[(long)(T_DIM - 1) * H_DIM + hh] = Hprev;
        c_fin[hh] = C;
    }
}

// -------------------- broadcast: out[t,b,:] = Hv[t,:]; tails hx=Hv[511], cx=Cfin
__global__ __launch_bounds__(256) void bc_kernel(
    const float* __restrict__ hv_tab, const float* __restrict__ c_fin,
    float* __restrict__ out)
{
    const int blk  = blockIdx.x;
    const int w    = threadIdx.x >> 6;
    const int lane = threadIdx.x & 63;

    const float* src;
    long base;
    int rbase;
    if (blk < 4 * T_DIM) {
        const int t = blk >> 2;
        rbase = (blk & 3) * 64;
        src = hv_tab + (long)t * H_DIM;
        base = (long)t * (B_DIM * H_DIM);
    } else {
        const int k = blk - 4 * T_DIM;        // 0..7
        rbase = (k & 3) * 64;
        src = (k < 4) ? (hv_tab + (long)(T_DIM - 1) * H_DIM) : c_fin;
        base = (long)T_DIM * (B_DIM * H_DIM) + (k < 4 ? 0 : (long)B_DIM * H_DIM);
    }
    const f32x4 v = ((const f32x4*)src)[lane];
    #pragma unroll
    for (int it = 0; it < 16; ++it) {
        const int row = rbase + w + 4 * it;
        __builtin_nontemporal_store(
            v, (f32x4*)(out + base + (long)row * H_DIM) + lane);
    }
}

extern "C" void kernel_launch(void* const* d_in, const int* in_sizes, int n_in,
                              void* d_out, int out_size, void* d_ws, size_t ws_size,
                              hipStream_t stream) {
    (void)in_sizes; (void)n_in; (void)out_size; (void)ws_size;
    const float* x   = (const float*)d_in[0];
    const float* Wf  = (const float*)d_in[1];
    const float* bf  = (const float*)d_in[2];
    const float* phf = (const float*)d_in[3];
    const float* Wi  = (const float*)d_in[4];
    const float* bi  = (const float*)d_in[5];
    const float* phi = (const float*)d_in[6];
    const float* Wu  = (const float*)d_in[7];
    const float* bu  = (const float*)d_in[8];
    const float* phu = (const float*)d_in[9];
    const float* Wo  = (const float*)d_in[10];
    const float* bo  = (const float*)d_in[11];
    const float* pho = (const float*)d_in[12];

    float* zx     = (float*)d_ws;                          // T*B*12 f = 6.29 MB
    float* hv_pad = zx + (size_t)T_DIM * B_DIM * NZ;       // 256 f scratch (t=0 store)
    float* hv_tab = hv_pad + H_DIM;                        // T*H f = 512 KB
    float* c_fin  = hv_tab + (size_t)T_DIM * H_DIM;        // H f = 1 KB

    zx_kernel<<<T_DIM, 256, 0, stream>>>(
        x, Wf, Wi, Wu, Wo, bf, bi, bu, bo, phf, phi, phu, pho, zx);

    rec_kernel<<<1, 512, 0, stream>>>(
        Wf, Wi, Wu, Wo, zx, hv_tab, c_fin);

    bc_kernel<<<4 * T_DIM + 8, 256, 0, stream>>>(hv_tab, c_fin, (float*)d_out);
}